// Round 6
// baseline (284.798 us; speedup 1.0000x reference)
//
#include <hip/hip_runtime.h>
#include <hip/hip_bf16.h>

#define N_NODES 50000
#define N_EDGES 800000
#define D 128
#define BN_EPS 1e-5f
#define ELLW 64            // max in-degree ~40 (Poisson 16); P(>64) ~ 1e-20
#define PROJ_LDK 136       // padded k-stride (ushorts) to break LDS bank conflicts
#define EPT 4              // edges per thread in fill

typedef __attribute__((ext_vector_type(8))) short bf16x8;
typedef __attribute__((ext_vector_type(4))) float f32x4;

__device__ inline float bf_lo(unsigned u) { union { unsigned x; float f; } c; c.x = u << 16; return c.f; }
__device__ inline float bf_hi(unsigned u) { union { unsigned x; float f; } c; c.x = u & 0xffff0000u; return c.f; }
__device__ inline unsigned short f2bf(float f) {
    union { float f; unsigned u; } c; c.f = f;
    unsigned u = c.u;
    u += 0x7fff + ((u >> 16) & 1);   // RNE
    return (unsigned short)(u >> 16);
}
__device__ inline unsigned pack2bf(float a, float b) {
    return (unsigned)f2bf(a) | ((unsigned)f2bf(b) << 16);
}

// ---------- kernel 1: ELL fill + both degree histograms, 4 edges/thread ------
__global__ __launch_bounds__(256) void fill_kernel(const int* __restrict__ src,
                                                   const int* __restrict__ dst,
                                                   int* __restrict__ cnt,
                                                   int* __restrict__ deg_out,
                                                   unsigned short* __restrict__ ell) {
    int e0 = blockIdx.x * (256 * EPT) + threadIdx.x;
    int s[EPT], t[EPT], pos[EPT];
    #pragma unroll
    for (int k = 0; k < EPT; ++k) {
        int e = e0 + k * 256;
        if (e < N_EDGES) { s[k] = src[e]; t[k] = dst[e]; }
        else             { s[k] = -1;     t[k] = 0;      }
    }
    // fire-and-forget out-degree histogram (no return value -> no vmcnt stall)
    #pragma unroll
    for (int k = 0; k < EPT; ++k)
        if (s[k] >= 0) atomicAdd(&deg_out[s[k]], 1);
    // independent returning atomics, issued back-to-back for latency overlap
    #pragma unroll
    for (int k = 0; k < EPT; ++k)
        if (s[k] >= 0) pos[k] = atomicAdd(&cnt[t[k]], 1);
    #pragma unroll
    for (int k = 0; k < EPT; ++k)
        if (s[k] >= 0 && pos[k] < ELLW)
            ell[(size_t)t[k] * ELLW + pos[k]] = (unsigned short)s[k];
}

// ---------- kernel 2: h = bf16((feat * norm_src) @ W) via MFMA ----------
__global__ __launch_bounds__(256, 2) void proj_kernel(const float* __restrict__ feat,
                                                      const float* __restrict__ W,
                                                      const int* __restrict__ deg_out,
                                                      unsigned short* __restrict__ h) {
    __shared__ unsigned short Wt[D * PROJ_LDK];
    __shared__ unsigned short As[64 * PROJ_LDK];
    __shared__ float nrmS[64];

    const int tid  = threadIdx.x;
    const int wave = tid >> 6;
    const int lane = tid & 63;
    const int quad = lane >> 4;
    const int l16  = lane & 15;

    for (int idx = tid; idx < D * D; idx += 256) {
        int k = idx >> 7, d = idx & 127;
        Wt[d * PROJ_LDK + k] = f2bf(W[idx]);
    }
    __syncthreads();

    bf16x8 breg[8][4];
    #pragma unroll
    for (int dt = 0; dt < 8; ++dt)
        #pragma unroll
        for (int kk = 0; kk < 4; ++kk)
            breg[dt][kk] = *(const bf16x8*)&Wt[(dt * 16 + l16) * PROJ_LDK + kk * 32 + quad * 8];

    const int n_tiles = (N_NODES + 63) / 64;   // 782
    for (int tile = blockIdx.x; tile < n_tiles; tile += gridDim.x) {
        const int base = tile * 64;
        __syncthreads();
        if (tid < 64) {
            int n = base + tid;
            int dg = (n < N_NODES) ? deg_out[n] : 1;
            nrmS[tid] = rsqrtf((float)(dg < 1 ? 1 : dg));
        }
        __syncthreads();
        for (int idx = tid; idx < 64 * 32; idx += 256) {
            int r = idx >> 5, c4 = idx & 31;
            int n = base + r;
            float4 v = (n < N_NODES) ? ((const float4*)(feat + (size_t)n * D))[c4]
                                     : make_float4(0.f, 0.f, 0.f, 0.f);
            float nm = nrmS[r];
            unsigned short* pp = &As[r * PROJ_LDK + c4 * 4];
            pp[0] = f2bf(v.x * nm); pp[1] = f2bf(v.y * nm);
            pp[2] = f2bf(v.z * nm); pp[3] = f2bf(v.w * nm);
        }
        __syncthreads();

        f32x4 acc[8];
        #pragma unroll
        for (int dt = 0; dt < 8; ++dt) acc[dt] = (f32x4){0.f, 0.f, 0.f, 0.f};

        #pragma unroll
        for (int kk = 0; kk < 4; ++kk) {
            bf16x8 af = *(const bf16x8*)&As[(wave * 16 + l16) * PROJ_LDK + kk * 32 + quad * 8];
            #pragma unroll
            for (int dt = 0; dt < 8; ++dt)
                acc[dt] = __builtin_amdgcn_mfma_f32_16x16x32_bf16(af, breg[dt][kk], acc[dt], 0, 0, 0);
        }

        #pragma unroll
        for (int dt = 0; dt < 8; ++dt) {
            #pragma unroll
            for (int r = 0; r < 4; ++r) {
                int n = base + wave * 16 + quad * 4 + r;
                if (n < N_NODES)
                    h[(size_t)n * D + dt * 16 + l16] = f2bf(acc[dt][r]);
            }
        }
    }
}

// ---------- kernel 3: SpMM gather (ushort ELL) + norm/bias/PReLU + BN --------
#define ACC8(v) { acc[0] += bf_lo((v).x); acc[1] += bf_hi((v).x); \
                  acc[2] += bf_lo((v).y); acc[3] += bf_hi((v).y); \
                  acc[4] += bf_lo((v).z); acc[5] += bf_hi((v).z); \
                  acc[6] += bf_lo((v).w); acc[7] += bf_hi((v).w); }

#define GATHER(sid) { uint4 vv = *(const uint4*)(h + (size_t)(sid) * D + coff); ACC8(vv); }

__global__ __launch_bounds__(256) void spmm_kernel(const int* __restrict__ cnt,
                                                   const unsigned short* __restrict__ ell,
                                                   const unsigned short* __restrict__ h,
                                                   const float* __restrict__ b,
                                                   const float* __restrict__ a1,
                                                   unsigned short* __restrict__ h2,
                                                   float* __restrict__ bn_sum,
                                                   float* __restrict__ bn_sumsq) {
    const int tid  = threadIdx.x;
    const int l16  = tid & 15;
    const int slot = (blockIdx.x * 256 + tid) >> 4;   // exactly one node per slot
    const float alpha = a1[0];
    const size_t coff = (size_t)l16 * 8;

    float bias[8];
    #pragma unroll
    for (int j = 0; j < 8; ++j) bias[j] = b[l16 * 8 + j];

    float lsum[8] = {0,0,0,0,0,0,0,0};
    float lsq[8]  = {0,0,0,0,0,0,0,0};

    const int n = slot;
    if (n < N_NODES) {
        int dg  = cnt[n];
        int end = (dg < ELLW) ? dg : ELLW;
        const unsigned short* row = ell + (size_t)n * ELLW;
        float acc[8] = {0,0,0,0,0,0,0,0};
        int i = 0;
        for (; i + 8 <= end; i += 8) {
            uint4 rw = *(const uint4*)(row + i);
            GATHER(rw.x & 0xffff); GATHER(rw.x >> 16);
            GATHER(rw.y & 0xffff); GATHER(rw.y >> 16);
            GATHER(rw.z & 0xffff); GATHER(rw.z >> 16);
            GATHER(rw.w & 0xffff); GATHER(rw.w >> 16);
        }
        for (; i < end; ++i) {
            GATHER(row[i]);
        }
        float nd = rsqrtf((float)(dg < 1 ? 1 : dg));
        float x[8];
        #pragma unroll
        for (int j = 0; j < 8; ++j) {
            float xv = acc[j] * nd + bias[j];
            xv = (xv >= 0.f) ? xv : alpha * xv;
            x[j] = xv;
            lsum[j] += xv;
            lsq[j]  += xv * xv;
        }
        // write h2 in bf16 (packed)
        uint4 o;
        o.x = pack2bf(x[0], x[1]);
        o.y = pack2bf(x[2], x[3]);
        o.z = pack2bf(x[4], x[5]);
        o.w = pack2bf(x[6], x[7]);
        *(uint4*)(h2 + (size_t)n * D + coff) = o;
    }

    // BN partials: reduce across 4 slots in wave, then 4 waves, then atomics
    #pragma unroll
    for (int j = 0; j < 8; ++j) {
        lsum[j] += __shfl_xor(lsum[j], 16);
        lsum[j] += __shfl_xor(lsum[j], 32);
        lsq[j]  += __shfl_xor(lsq[j], 16);
        lsq[j]  += __shfl_xor(lsq[j], 32);
    }
    __shared__ float red[4][256];
    const int wave = tid >> 6;
    const int lane = tid & 63;
    if (lane < 16) {
        #pragma unroll
        for (int j = 0; j < 8; ++j) {
            red[wave][l16 * 16 + j]     = lsum[j];
            red[wave][l16 * 16 + 8 + j] = lsq[j];
        }
    }
    __syncthreads();
    {
        float tot = red[0][tid] + red[1][tid] + red[2][tid] + red[3][tid];
        int l = tid >> 4;
        int v = tid & 15;
        int dim = l * 8 + (v & 7);
        if (v < 8) atomicAdd(&bn_sum[dim], tot);
        else       atomicAdd(&bn_sumsq[dim], tot);
    }
}

// ---------- kernel 4: BN finalize + PReLU (bf16 in, fp32 out) ----------
__global__ __launch_bounds__(256) void final_kernel(const unsigned short* __restrict__ h2,
                                                    const float* __restrict__ bn_sum,
                                                    const float* __restrict__ bn_sumsq,
                                                    const float* __restrict__ gamma,
                                                    const float* __restrict__ beta,
                                                    const float* __restrict__ a2,
                                                    float* __restrict__ out) {
    int i8 = blockIdx.x * 256 + threadIdx.x;   // one thread per 8 elements
    if (i8 < N_NODES * D / 8) {
        int dbase = (i8 * 8) & (D - 1);
        const float invN = 1.0f / (float)N_NODES;
        const float alpha = a2[0];
        uint4 v = ((const uint4*)h2)[i8];
        float xv[8] = { bf_lo(v.x), bf_hi(v.x), bf_lo(v.y), bf_hi(v.y),
                        bf_lo(v.z), bf_hi(v.z), bf_lo(v.w), bf_hi(v.w) };
        float r[8];
        #pragma unroll
        for (int j = 0; j < 8; ++j) {
            int d = dbase + j;
            float mean = bn_sum[d] * invN;
            float var  = bn_sumsq[d] * invN - mean * mean;
            float inv  = rsqrtf(var + BN_EPS);
            float t = (xv[j] - mean) * inv * gamma[d] + beta[d];
            r[j] = (t >= 0.f) ? t : alpha * t;
        }
        float4* po = (float4*)(out + (size_t)i8 * 8);
        po[0] = make_float4(r[0], r[1], r[2], r[3]);
        po[1] = make_float4(r[4], r[5], r[6], r[7]);
    }
}

extern "C" void kernel_launch(void* const* d_in, const int* in_sizes, int n_in,
                              void* d_out, int out_size, void* d_ws, size_t ws_size,
                              hipStream_t stream) {
    const float* feat  = (const float*)d_in[0];
    const int*   src   = (const int*)  d_in[1];
    const int*   dst   = (const int*)  d_in[2];
    const float* W     = (const float*)d_in[3];
    const float* b     = (const float*)d_in[4];
    const float* a1    = (const float*)d_in[5];
    const float* gamma = (const float*)d_in[6];
    const float* beta  = (const float*)d_in[7];
    const float* a2    = (const float*)d_in[8];
    float* out = (float*)d_out;

    // Workspace layout (bytes). First 401024 B zeroed in one memset:
    //   cnt (200000) | deg_out (200000) | bn_sum (512) | bn_sumsq (512)
    char* ws = (char*)d_ws;
    int*            cnt       = (int*)(ws + 0);
    int*            deg_out_p = (int*)(ws + 200000);
    float*          bn_sum    = (float*)(ws + 400000);
    float*          bn_sumsq  = (float*)(ws + 400512);
    unsigned short* ell       = (unsigned short*)(ws + 401024);   // 50000*64*2 = 6.4 MB
    unsigned short* h         = (unsigned short*)(ws + 6801024);  // 12.8 MB bf16
    unsigned short* h2        = (unsigned short*)(ws + 19601024); // 12.8 MB bf16

    hipMemsetAsync(ws, 0, 401024, stream);

    // 1) ELL fill + degree histograms (4 edges/thread)
    fill_kernel<<<(N_EDGES + 256 * EPT - 1) / (256 * EPT), 256, 0, stream>>>(
        src, dst, cnt, deg_out_p, ell);

    // 2) projection (MFMA bf16): 391 blocks x 2 tiles each = 782 tiles, balanced
    proj_kernel<<<391, 256, 0, stream>>>(feat, W, deg_out_p, h);

    // 3) SpMM gather + fused node-wise ops + BN partials (1 node per 16-lane slot)
    spmm_kernel<<<3125, 256, 0, stream>>>(cnt, ell, h, b, a1, h2, bn_sum, bn_sumsq);

    // 4) BN finalize + PReLU
    final_kernel<<<(N_NODES * D / 8 + 255) / 256, 256, 0, stream>>>(h2, bn_sum, bn_sumsq,
                                                                    gamma, beta, a2, out);
}

// Round 7
// 234.628 us; speedup vs baseline: 1.2138x; 1.2138x over previous
//
#include <hip/hip_runtime.h>
#include <hip/hip_bf16.h>

#define N_NODES 50000
#define N_EDGES 800000
#define D 128
#define BN_EPS 1e-5f
#define ELLW 64            // max in-degree ~40 (Poisson 16); P(>64) negligible
#define PROJ_LDK 136       // padded k-stride (ushorts) to break LDS bank conflicts
#define EPT 8              // edges per thread in fill
#define SPMM_BLOCKS 1564   // 1564*16 slots = 25024 >= 25000 node pairs

typedef __attribute__((ext_vector_type(8))) short bf16x8;
typedef __attribute__((ext_vector_type(4))) float f32x4;

__device__ inline float bf_lo(unsigned u) { union { unsigned x; float f; } c; c.x = u << 16; return c.f; }
__device__ inline float bf_hi(unsigned u) { union { unsigned x; float f; } c; c.x = u & 0xffff0000u; return c.f; }
__device__ inline unsigned short f2bf(float f) {
    union { float f; unsigned u; } c; c.f = f;
    unsigned u = c.u;
    u += 0x7fff + ((u >> 16) & 1);   // RNE
    return (unsigned short)(u >> 16);
}
__device__ inline unsigned pack2bf(float a, float b) {
    return (unsigned)f2bf(a) | ((unsigned)f2bf(b) << 16);
}

// ---------- kernel 1: ELL fill + both degree histograms, 8 edges/thread ------
__global__ __launch_bounds__(256) void fill_kernel(const int* __restrict__ src,
                                                   const int* __restrict__ dst,
                                                   int* __restrict__ cnt,
                                                   int* __restrict__ deg_out,
                                                   unsigned short* __restrict__ ell) {
    int e0 = blockIdx.x * (256 * EPT) + threadIdx.x;
    int s[EPT], t[EPT], pos[EPT];
    #pragma unroll
    for (int k = 0; k < EPT; ++k) {
        int e = e0 + k * 256;
        if (e < N_EDGES) { s[k] = src[e]; t[k] = dst[e]; }
        else             { s[k] = -1;     t[k] = 0;      }
    }
    // fire-and-forget out-degree histogram (no return value -> no vmcnt stall)
    #pragma unroll
    for (int k = 0; k < EPT; ++k)
        if (s[k] >= 0) atomicAdd(&deg_out[s[k]], 1);
    // independent returning atomics, issued back-to-back for latency overlap
    #pragma unroll
    for (int k = 0; k < EPT; ++k)
        if (s[k] >= 0) pos[k] = atomicAdd(&cnt[t[k]], 1);
    #pragma unroll
    for (int k = 0; k < EPT; ++k)
        if (s[k] >= 0 && pos[k] < ELLW)
            ell[(size_t)t[k] * ELLW + pos[k]] = (unsigned short)s[k];
}

// ---------- kernel 2: h = bf16((feat * norm_src) @ W) via MFMA ----------
__global__ __launch_bounds__(256, 2) void proj_kernel(const float* __restrict__ feat,
                                                      const float* __restrict__ W,
                                                      const int* __restrict__ deg_out,
                                                      unsigned short* __restrict__ h) {
    __shared__ unsigned short Wt[D * PROJ_LDK];
    __shared__ unsigned short As[64 * PROJ_LDK];
    __shared__ float nrmS[64];

    const int tid  = threadIdx.x;
    const int wave = tid >> 6;
    const int lane = tid & 63;
    const int quad = lane >> 4;
    const int l16  = lane & 15;

    for (int idx = tid; idx < D * D; idx += 256) {
        int k = idx >> 7, d = idx & 127;
        Wt[d * PROJ_LDK + k] = f2bf(W[idx]);
    }
    __syncthreads();

    bf16x8 breg[8][4];
    #pragma unroll
    for (int dt = 0; dt < 8; ++dt)
        #pragma unroll
        for (int kk = 0; kk < 4; ++kk)
            breg[dt][kk] = *(const bf16x8*)&Wt[(dt * 16 + l16) * PROJ_LDK + kk * 32 + quad * 8];

    const int n_tiles = (N_NODES + 63) / 64;   // 782
    for (int tile = blockIdx.x; tile < n_tiles; tile += gridDim.x) {
        const int base = tile * 64;
        __syncthreads();
        if (tid < 64) {
            int n = base + tid;
            int dg = (n < N_NODES) ? deg_out[n] : 1;
            nrmS[tid] = rsqrtf((float)(dg < 1 ? 1 : dg));
        }
        __syncthreads();
        for (int idx = tid; idx < 64 * 32; idx += 256) {
            int r = idx >> 5, c4 = idx & 31;
            int n = base + r;
            float4 v = (n < N_NODES) ? ((const float4*)(feat + (size_t)n * D))[c4]
                                     : make_float4(0.f, 0.f, 0.f, 0.f);
            float nm = nrmS[r];
            unsigned short* pp = &As[r * PROJ_LDK + c4 * 4];
            pp[0] = f2bf(v.x * nm); pp[1] = f2bf(v.y * nm);
            pp[2] = f2bf(v.z * nm); pp[3] = f2bf(v.w * nm);
        }
        __syncthreads();

        f32x4 acc[8];
        #pragma unroll
        for (int dt = 0; dt < 8; ++dt) acc[dt] = (f32x4){0.f, 0.f, 0.f, 0.f};

        #pragma unroll
        for (int kk = 0; kk < 4; ++kk) {
            bf16x8 af = *(const bf16x8*)&As[(wave * 16 + l16) * PROJ_LDK + kk * 32 + quad * 8];
            #pragma unroll
            for (int dt = 0; dt < 8; ++dt)
                acc[dt] = __builtin_amdgcn_mfma_f32_16x16x32_bf16(af, breg[dt][kk], acc[dt], 0, 0, 0);
        }

        #pragma unroll
        for (int dt = 0; dt < 8; ++dt) {
            #pragma unroll
            for (int r = 0; r < 4; ++r) {
                int n = base + wave * 16 + quad * 4 + r;
                if (n < N_NODES)
                    h[(size_t)n * D + dt * 16 + l16] = f2bf(acc[dt][r]);
            }
        }
    }
}

// ---------- kernel 3: SpMM gather, node-PAIR interleaved per slot ----------
#define ACCA(v) { accA[0] += bf_lo((v).x); accA[1] += bf_hi((v).x); \
                  accA[2] += bf_lo((v).y); accA[3] += bf_hi((v).y); \
                  accA[4] += bf_lo((v).z); accA[5] += bf_hi((v).z); \
                  accA[6] += bf_lo((v).w); accA[7] += bf_hi((v).w); }
#define ACCB(v) { accB[0] += bf_lo((v).x); accB[1] += bf_hi((v).x); \
                  accB[2] += bf_lo((v).y); accB[3] += bf_hi((v).y); \
                  accB[4] += bf_lo((v).z); accB[5] += bf_hi((v).z); \
                  accB[6] += bf_lo((v).w); accB[7] += bf_hi((v).w); }
#define GA(sid) { uint4 vv = *(const uint4*)(h + (size_t)(sid) * D + coff); ACCA(vv); }
#define GB(sid) { uint4 vv = *(const uint4*)(h + (size_t)(sid) * D + coff); ACCB(vv); }

__global__ __launch_bounds__(256) void spmm_kernel(const int* __restrict__ cnt,
                                                   const unsigned short* __restrict__ ell,
                                                   const unsigned short* __restrict__ h,
                                                   const float* __restrict__ b,
                                                   const float* __restrict__ a1,
                                                   unsigned short* __restrict__ h2,
                                                   float* __restrict__ bn_sum,
                                                   float* __restrict__ bn_sumsq) {
    const int tid  = threadIdx.x;
    const int l16  = tid & 15;
    const int slot = (blockIdx.x * 256 + tid) >> 4;   // pair index
    const float alpha = a1[0];
    const size_t coff = (size_t)l16 * 8;

    float bias[8];
    #pragma unroll
    for (int j = 0; j < 8; ++j) bias[j] = b[l16 * 8 + j];

    float lsum[8] = {0,0,0,0,0,0,0,0};
    float lsq[8]  = {0,0,0,0,0,0,0,0};

    if (slot < N_NODES / 2) {
        const int n0 = slot * 2;
        const int n1 = n0 + 1;
        int dgA = cnt[n0], dgB = cnt[n1];
        int endA = (dgA < ELLW) ? dgA : ELLW;
        int endB = (dgB < ELLW) ? dgB : ELLW;
        const unsigned short* rowA = ell + (size_t)n0 * ELLW;
        const unsigned short* rowB = ell + (size_t)n1 * ELLW;

        float accA[8] = {0,0,0,0,0,0,0,0};
        float accB[8] = {0,0,0,0,0,0,0,0};
        int iA = 0, iB = 0;

        // joint 8-batches: 2 row loads then 16 independent gathers in flight
        while (iA + 8 <= endA && iB + 8 <= endB) {
            uint4 ra = *(const uint4*)(rowA + iA);
            uint4 rb = *(const uint4*)(rowB + iB);
            GA(ra.x & 0xffff); GA(ra.x >> 16);
            GA(ra.y & 0xffff); GA(ra.y >> 16);
            GA(ra.z & 0xffff); GA(ra.z >> 16);
            GA(ra.w & 0xffff); GA(ra.w >> 16);
            GB(rb.x & 0xffff); GB(rb.x >> 16);
            GB(rb.y & 0xffff); GB(rb.y >> 16);
            GB(rb.z & 0xffff); GB(rb.z >> 16);
            GB(rb.w & 0xffff); GB(rb.w >> 16);
            iA += 8; iB += 8;
        }
        for (; iA + 8 <= endA; iA += 8) {
            uint4 ra = *(const uint4*)(rowA + iA);
            GA(ra.x & 0xffff); GA(ra.x >> 16);
            GA(ra.y & 0xffff); GA(ra.y >> 16);
            GA(ra.z & 0xffff); GA(ra.z >> 16);
            GA(ra.w & 0xffff); GA(ra.w >> 16);
        }
        for (; iB + 8 <= endB; iB += 8) {
            uint4 rb = *(const uint4*)(rowB + iB);
            GB(rb.x & 0xffff); GB(rb.x >> 16);
            GB(rb.y & 0xffff); GB(rb.y >> 16);
            GB(rb.z & 0xffff); GB(rb.z >> 16);
            GB(rb.w & 0xffff); GB(rb.w >> 16);
        }
        for (; iA < endA; ++iA) { GA(rowA[iA]); }
        for (; iB < endB; ++iB) { GB(rowB[iB]); }

        float ndA = rsqrtf((float)(dgA < 1 ? 1 : dgA));
        float ndB = rsqrtf((float)(dgB < 1 ? 1 : dgB));
        float xA[8], xB[8];
        #pragma unroll
        for (int j = 0; j < 8; ++j) {
            float va = accA[j] * ndA + bias[j];
            va = (va >= 0.f) ? va : alpha * va;
            xA[j] = va; lsum[j] += va; lsq[j] += va * va;
            float vb = accB[j] * ndB + bias[j];
            vb = (vb >= 0.f) ? vb : alpha * vb;
            xB[j] = vb; lsum[j] += vb; lsq[j] += vb * vb;
        }
        uint4 oA, oB;
        oA.x = pack2bf(xA[0], xA[1]); oA.y = pack2bf(xA[2], xA[3]);
        oA.z = pack2bf(xA[4], xA[5]); oA.w = pack2bf(xA[6], xA[7]);
        oB.x = pack2bf(xB[0], xB[1]); oB.y = pack2bf(xB[2], xB[3]);
        oB.z = pack2bf(xB[4], xB[5]); oB.w = pack2bf(xB[6], xB[7]);
        *(uint4*)(h2 + (size_t)n0 * D + coff) = oA;
        *(uint4*)(h2 + (size_t)n1 * D + coff) = oB;
    }

    // BN partials: reduce across 4 slots in wave, then 4 waves, then atomics
    #pragma unroll
    for (int j = 0; j < 8; ++j) {
        lsum[j] += __shfl_xor(lsum[j], 16);
        lsum[j] += __shfl_xor(lsum[j], 32);
        lsq[j]  += __shfl_xor(lsq[j], 16);
        lsq[j]  += __shfl_xor(lsq[j], 32);
    }
    __shared__ float red[4][256];
    const int wave = tid >> 6;
    const int lane = tid & 63;
    if (lane < 16) {
        #pragma unroll
        for (int j = 0; j < 8; ++j) {
            red[wave][l16 * 16 + j]     = lsum[j];
            red[wave][l16 * 16 + 8 + j] = lsq[j];
        }
    }
    __syncthreads();
    {
        float tot = red[0][tid] + red[1][tid] + red[2][tid] + red[3][tid];
        int l = tid >> 4;
        int v = tid & 15;
        int dim = l * 8 + (v & 7);
        int rep = (blockIdx.x & 3) * D;    // 4-way replicated accumulators
        if (v < 8) atomicAdd(&bn_sum[rep + dim], tot);
        else       atomicAdd(&bn_sumsq[rep + dim], tot);
    }
}

// ---------- kernel 4: BN finalize + PReLU (bf16 in, fp32 out) ----------
__global__ __launch_bounds__(256) void final_kernel(const unsigned short* __restrict__ h2,
                                                    const float* __restrict__ bn_sum,
                                                    const float* __restrict__ bn_sumsq,
                                                    const float* __restrict__ gamma,
                                                    const float* __restrict__ beta,
                                                    const float* __restrict__ a2,
                                                    float* __restrict__ out) {
    int i8 = blockIdx.x * 256 + threadIdx.x;   // one thread per 8 elements
    if (i8 < N_NODES * D / 8) {
        int dbase = (i8 * 8) & (D - 1);
        const float invN = 1.0f / (float)N_NODES;
        const float alpha = a2[0];
        uint4 v = ((const uint4*)h2)[i8];
        float xv[8] = { bf_lo(v.x), bf_hi(v.x), bf_lo(v.y), bf_hi(v.y),
                        bf_lo(v.z), bf_hi(v.z), bf_lo(v.w), bf_hi(v.w) };
        float r[8];
        #pragma unroll
        for (int j = 0; j < 8; ++j) {
            int d = dbase + j;
            float sm = bn_sum[d] + bn_sum[D + d] + bn_sum[2 * D + d] + bn_sum[3 * D + d];
            float sq = bn_sumsq[d] + bn_sumsq[D + d] + bn_sumsq[2 * D + d] + bn_sumsq[3 * D + d];
            float mean = sm * invN;
            float var  = sq * invN - mean * mean;
            float inv  = rsqrtf(var + BN_EPS);
            float t = (xv[j] - mean) * inv * gamma[d] + beta[d];
            r[j] = (t >= 0.f) ? t : alpha * t;
        }
        float4* po = (float4*)(out + (size_t)i8 * 8);
        po[0] = make_float4(r[0], r[1], r[2], r[3]);
        po[1] = make_float4(r[4], r[5], r[6], r[7]);
    }
}

extern "C" void kernel_launch(void* const* d_in, const int* in_sizes, int n_in,
                              void* d_out, int out_size, void* d_ws, size_t ws_size,
                              hipStream_t stream) {
    const float* feat  = (const float*)d_in[0];
    const int*   src   = (const int*)  d_in[1];
    const int*   dst   = (const int*)  d_in[2];
    const float* W     = (const float*)d_in[3];
    const float* b     = (const float*)d_in[4];
    const float* a1    = (const float*)d_in[5];
    const float* gamma = (const float*)d_in[6];
    const float* beta  = (const float*)d_in[7];
    const float* a2    = (const float*)d_in[8];
    float* out = (float*)d_out;

    // Workspace layout (bytes). First 404096 B zeroed in one memset:
    //   cnt (200000) | deg_out (200000) | bn_sum (4*128*4) | bn_sumsq (4*128*4)
    char* ws = (char*)d_ws;
    int*            cnt       = (int*)(ws + 0);
    int*            deg_out_p = (int*)(ws + 200000);
    float*          bn_sum    = (float*)(ws + 400000);
    float*          bn_sumsq  = (float*)(ws + 402048);
    unsigned short* ell       = (unsigned short*)(ws + 404096);   // 6.4 MB
    unsigned short* h         = (unsigned short*)(ws + 6804096);  // 12.8 MB bf16
    unsigned short* h2        = (unsigned short*)(ws + 19604096); // 12.8 MB bf16

    hipMemsetAsync(ws, 0, 404096, stream);

    // 1) ELL fill + degree histograms (8 edges/thread)
    fill_kernel<<<(N_EDGES + 256 * EPT - 1) / (256 * EPT), 256, 0, stream>>>(
        src, dst, cnt, deg_out_p, ell);

    // 2) projection (MFMA bf16): 391 blocks x 2 tiles each = 782 tiles
    proj_kernel<<<391, 256, 0, stream>>>(feat, W, deg_out_p, h);

    // 3) SpMM gather, node-pair interleaved + BN partials (4-way replicated)
    spmm_kernel<<<SPMM_BLOCKS, 256, 0, stream>>>(cnt, ell, h, b, a1, h2, bn_sum, bn_sumsq);

    // 4) BN finalize + PReLU
    final_kernel<<<(N_NODES * D / 8 + 255) / 256, 256, 0, stream>>>(h2, bn_sum, bn_sumsq,
                                                                    gamma, beta, a2, out);
}